// Round 1
// baseline (25732.532 us; speedup 1.0000x reference)
//
#include <hip/hip_runtime.h>
#include <math.h>

#define NTOK 4096
#define DIM 1024
#define NCOL 65536
#define RANK 128
#define CK 20
#define FK 10

#define TT 64          // tokens per K1 block
#define CTILES 8       // column tiles (blockIdx.y)
#define CPT 8192       // columns per tile
#define NCG 32         // column groups per tile (CPT / 256)

// ---------------------------------------------------------------------------
// K1: router logits (f32, exact) fused with per-(token, col-tile) top-20.
// Block: 256 threads, 64 tokens x 8192 columns. Thread owns 1 column/group,
// 64 token accumulators. x read via wave-uniform addresses -> s_load (SGPR),
// W_router reads coalesced, reused 64x from registers.
// ---------------------------------------------------------------------------
__global__ __launch_bounds__(256, 2)
void k1_router(const float* __restrict__ x, const float* __restrict__ Wr,
               float* __restrict__ part_s, int* __restrict__ part_i)
{
    __shared__ float smem[TT][257];   // 65792 B; reused for list merge at end

    const int tid     = threadIdx.x;
    const int tokbase = blockIdx.x * TT;
    const int colbase = blockIdx.y * CPT;
    const int mytok   = tid & 63;
    const int mypart  = tid >> 6;

    // per-thread running top-20 for (mytok, mypart quarter of columns),
    // sorted descending; ties impossible within a part (strictly increasing idx)
    float ts[CK]; int ti[CK];
#pragma unroll
    for (int k = 0; k < CK; ++k) { ts[k] = -INFINITY; ti[k] = 0x7fffffff; }

#pragma unroll 1
    for (int cg = 0; cg < NCG; ++cg) {
        const int n = colbase + cg * 256 + tid;
        float acc[TT];
#pragma unroll
        for (int t = 0; t < TT; ++t) acc[t] = 0.0f;

#pragma unroll 1
        for (int dc = 0; dc < DIM; dc += 8) {
            float w[8];
#pragma unroll
            for (int i = 0; i < 8; ++i)
                w[i] = Wr[(size_t)(dc + i) * NCOL + n];
#pragma unroll
            for (int t = 0; t < TT; ++t) {
                const float* xr = x + (size_t)(tokbase + t) * DIM + dc;  // wave-uniform -> s_load
#pragma unroll
                for (int i = 0; i < 8; ++i)
                    acc[t] = fmaf(xr[i], w[i], acc[t]);
            }
        }

        __syncthreads();   // previous selection reads done before overwrite
#pragma unroll
        for (int t = 0; t < TT; ++t) smem[t][tid] = acc[t];
        __syncthreads();

        const int jbase = mypart * 64;
#pragma unroll 1
        for (int j = 0; j < 64; ++j) {
            float v = smem[mytok][jbase + j];
            if (v > ts[CK - 1]) {          // strict: new (higher idx) loses ties
                float cv = v;
                int   ci = colbase + cg * 256 + jbase + j;
#pragma unroll
                for (int k = 0; k < CK; ++k) {
                    bool  g  = cv > ts[k];
                    float os = ts[k]; int oi = ti[k];
                    ts[k] = g ? cv : os;  ti[k] = g ? ci : oi;
                    cv    = g ? os : cv;  ci    = g ? oi : ci;
                }
            }
        }
    }

    // merge the 4 per-part sorted lists per token -> top-20 for this col-tile
    __syncthreads();
    float* Ls = &smem[0][0];
    int*   Li = (int*)(Ls + 256 * CK);
#pragma unroll
    for (int k = 0; k < CK; ++k) { Ls[tid * CK + k] = ts[k]; Li[tid * CK + k] = ti[k]; }
    __syncthreads();

    if (tid < TT) {
        const int tok = tid;
        int h0 = 0, h1 = 0, h2 = 0, h3 = 0;
        const size_t ob = ((size_t)(tokbase + tok) * CTILES + blockIdx.y) * CK;
#pragma unroll 1
        for (int k = 0; k < CK; ++k) {
            float s0 = Ls[(      tok) * CK + h0]; int i0 = Li[(      tok) * CK + h0];
            float s1 = Ls[( 64 + tok) * CK + h1]; int i1 = Li[( 64 + tok) * CK + h1];
            float s2 = Ls[(128 + tok) * CK + h2]; int i2 = Li[(128 + tok) * CK + h2];
            float s3 = Ls[(192 + tok) * CK + h3]; int i3 = Li[(192 + tok) * CK + h3];
            float bs = s0; int bi = i0; int bp = 0;
            if (s1 > bs || (s1 == bs && i1 < bi)) { bs = s1; bi = i1; bp = 1; }
            if (s2 > bs || (s2 == bs && i2 < bi)) { bs = s2; bi = i2; bp = 2; }
            if (s3 > bs || (s3 == bs && i3 < bi)) { bs = s3; bi = i3; bp = 3; }
            part_s[ob + k] = bs; part_i[ob + k] = bi;
            if      (bp == 0) ++h0;
            else if (bp == 1) ++h1;
            else if (bp == 2) ++h2;
            else              ++h3;
        }
    }
}

// ---------------------------------------------------------------------------
// K3: per-token final stage. Merge 8x20 partials (exact lex rank), query =
// x . W_enc, fine scores on 20 gathered K rows, top-10 + softmax, weighted
// coalesced gather of 10 V rows.
// ---------------------------------------------------------------------------
__global__ __launch_bounds__(256)
void k3_fine(const float* __restrict__ x, const float* __restrict__ Wenc,
             const float* __restrict__ Kall, const float* __restrict__ Vall,
             const float* __restrict__ part_s, const int* __restrict__ part_i,
             float* __restrict__ out)
{
    const int tok = blockIdx.x;
    const int tid = threadIdx.x;

    __shared__ float xs[DIM];
    __shared__ float qs[RANK];
    __shared__ float ls[CTILES * CK];
    __shared__ int   li[CTILES * CK];
    __shared__ int   cand[CK];
    __shared__ float fsc[CK];
    __shared__ float fss[FK];
    __shared__ int   fgi[FK];
    __shared__ float fw[FK];

    ((float4*)xs)[tid] = ((const float4*)(x + (size_t)tok * DIM))[tid];
    if (tid < CTILES * CK) {
        ls[tid] = part_s[(size_t)tok * (CTILES * CK) + tid];
        li[tid] = part_i[(size_t)tok * (CTILES * CK) + tid];
    }
    __syncthreads();

    // exact top-20 of 160 via lex rank (ranks unique: idx distinct)
    if (tid < CTILES * CK) {
        float s = ls[tid]; int idx = li[tid];
        int r = 0;
        for (int e = 0; e < CTILES * CK; ++e) {
            float s2 = ls[e]; int i2 = li[e];
            r += (s2 > s) || (s2 == s && i2 < idx);
        }
        if (r < CK) cand[r] = idx;
    }
    __syncthreads();

    // query = x . W_enc   (xs broadcast from LDS, W_enc coalesced)
    if (tid < RANK) {
        float q = 0.0f;
#pragma unroll 8
        for (int d = 0; d < DIM; ++d)
            q = fmaf(xs[d], Wenc[(size_t)d * RANK + tid], q);
        qs[tid] = q;
    }
    __syncthreads();

    // fine scores for the 20 candidates
    if (tid < CK) {
        const float* Kr = Kall + (size_t)cand[tid] * RANK;
        float s = 0.0f;
#pragma unroll 8
        for (int r = 0; r < RANK; ++r) s = fmaf(qs[r], Kr[r], s);
        fsc[tid] = s * 0.08838834764831845f;   // 1/sqrt(128)
    }
    __syncthreads();

    // exact top-10 of 20 via lex rank (tie -> lower candidate position)
    if (tid < CK) {
        float s = fsc[tid]; int r = 0;
        for (int e = 0; e < CK; ++e)
            r += (fsc[e] > s) || (fsc[e] == s && e < tid);
        if (r < FK) { fss[r] = s; fgi[r] = cand[tid]; }
    }
    __syncthreads();

    if (tid == 0) {
        float m = fss[0];
#pragma unroll
        for (int k = 1; k < FK; ++k) m = fmaxf(m, fss[k]);
        float w[FK]; float sum = 0.0f;
#pragma unroll
        for (int k = 0; k < FK; ++k) { w[k] = expf(fss[k] - m); sum += w[k]; }
        float inv = 1.0f / sum;
#pragma unroll
        for (int k = 0; k < FK; ++k) fw[k] = w[k] * inv;
    }
    __syncthreads();

    // output = sum_f w[f] * V[g[f]]   (coalesced V rows)
#pragma unroll
    for (int jj = 0; jj < DIM / 256; ++jj) {
        const int d = tid + jj * 256;
        float o = 0.0f;
#pragma unroll
        for (int f = 0; f < FK; ++f)
            o = fmaf(fw[f], Vall[(size_t)fgi[f] * DIM + d], o);
        out[(size_t)tok * DIM + d] = o;
    }
}

extern "C" void kernel_launch(void* const* d_in, const int* in_sizes, int n_in,
                              void* d_out, int out_size, void* d_ws, size_t ws_size,
                              hipStream_t stream)
{
    (void)in_sizes; (void)n_in; (void)out_size; (void)ws_size;
    const float* x    = (const float*)d_in[0];
    const float* Wr   = (const float*)d_in[1];
    const float* Wenc = (const float*)d_in[2];
    const float* Kall = (const float*)d_in[3];
    const float* Vall = (const float*)d_in[4];
    float* out = (float*)d_out;

    float* part_s = (float*)d_ws;                                  // 4096*8*20 f32
    int*   part_i = (int*)d_ws + (size_t)NTOK * CTILES * CK;       // 4096*8*20 i32

    dim3 g1(NTOK / TT, CTILES);
    k1_router<<<g1, 256, 0, stream>>>(x, Wr, part_s, part_i);
    k3_fine<<<NTOK, 256, 0, stream>>>(x, Wenc, Kall, Vall, part_s, part_i, out);
}

// Round 2
// 2762.365 us; speedup vs baseline: 9.3154x; 9.3154x over previous
//
#include <hip/hip_runtime.h>
#include <math.h>
#include <stdint.h>

#define NTOK 4096
#define DIM  1024
#define NCOL 65536
#define RANK 128
#define CK 20
#define FK 10

// ---- Path A (MFMA) geometry ----
#define SLABS 16
#define SLABCOLS (NCOL / SLABS)      // 4096
#define BM 128
#define CHUNK 256
#define BK 32
#define NCHUNK (SLABCOLS / CHUNK)    // 16
#define KSTEPS (DIM / BK)            // 32

typedef _Float16 f16;
typedef __attribute__((ext_vector_type(8))) _Float16 f16x8;
typedef __attribute__((ext_vector_type(4))) float f32x4;

__device__ __forceinline__ void f32_split(float v, unsigned short& h, unsigned short& l) {
    f16 hh = (f16)v;
    float r = v - (float)hh;
    f16 ll = (f16)r;
    h = __builtin_bit_cast(unsigned short, hh);
    l = __builtin_bit_cast(unsigned short, ll);
}

__device__ __forceinline__ void gll16(const void* src, void* ldsdst) {
    __builtin_amdgcn_global_load_lds(
        (__attribute__((address_space(1))) unsigned int*)src,
        (__attribute__((address_space(3))) unsigned int*)ldsdst, 16, 0, 0);
}

// ---------------------------------------------------------------------------
// K0x: x -> f16 hi/lo planes, layout [t][k]
// ---------------------------------------------------------------------------
__global__ __launch_bounds__(256)
void k0_convx(const float* __restrict__ x, unsigned short* __restrict__ xh,
              unsigned short* __restrict__ xl)
{
    int i = blockIdx.x * 256 + threadIdx.x;   // float4 index
    float4 v = ((const float4*)x)[i];
    ushort4 h, l;
    f32_split(v.x, h.x, l.x); f32_split(v.y, h.y, l.y);
    f32_split(v.z, h.z, l.z); f32_split(v.w, h.w, l.w);
    ((ushort4*)xh)[i] = h;
    ((ushort4*)xl)[i] = l;
}

// ---------------------------------------------------------------------------
// K0w: W[k][n] f32 -> WhT[n][k], WlT[n][k]  (f16 bits, scaled x1024), 64x64 tiles
// ---------------------------------------------------------------------------
__global__ __launch_bounds__(256)
void k0_convw(const float* __restrict__ W, unsigned short* __restrict__ WhT,
              unsigned short* __restrict__ WlT)
{
    __shared__ float t[64][65];
    const int tid = threadIdx.x;
    const int k0 = blockIdx.x * 64;
    const int n0 = blockIdx.y * 64;
#pragma unroll
    for (int i = 0; i < 16; ++i) {
        int idx = i * 256 + tid;
        int r = idx >> 6, c = idx & 63;
        t[r][c] = W[(size_t)(k0 + r) * NCOL + n0 + c];
    }
    __syncthreads();
#pragma unroll
    for (int i = 0; i < 8; ++i) {
        int idx = i * 256 + tid;
        int n = idx >> 5, kp = idx & 31;
        float a = t[2 * kp][n]     * 1024.0f;
        float b = t[2 * kp + 1][n] * 1024.0f;
        unsigned short ah, al, bh, bl;
        f32_split(a, ah, al);
        f32_split(b, bh, bl);
        unsigned int wh = (unsigned)ah | ((unsigned)bh << 16);
        unsigned int wl = (unsigned)al | ((unsigned)bl << 16);
        size_t row = (size_t)(n0 + n) * DIM + k0;
        *(unsigned int*)(WhT + row + 2 * kp) = wh;
        *(unsigned int*)(WlT + row + 2 * kp) = wl;
    }
}

// ---------------------------------------------------------------------------
// K1: split-f16 MFMA router logits + fused per-(token, slab) top-20.
// 512 thr (8 waves, 2x4 wave grid), tile 128 tok x 256 cols/chunk, BK=32,
// double-buffered global_load_lds staging, 3 MFMA passes (hh, hl, lh).
// ---------------------------------------------------------------------------
__global__ __launch_bounds__(512)
void k1_mfma(const unsigned short* __restrict__ xh, const unsigned short* __restrict__ xl,
             const unsigned short* __restrict__ WhT, const unsigned short* __restrict__ WlT,
             float* __restrict__ part_s, int* __restrict__ part_i)
{
    // layout: two 48KB staging buffers at 0 and 49152.
    // within a buffer: Ah 0(8KB), Al 8192, Bh 16384(16KB), Bl 32768(16KB)
    // sel region (128 x 130 f32 = 66560B) at 49152 (aliases buffer 1)
    // list region (512 lists) at 0 after all chunks done
    __shared__ __align__(16) unsigned char smem[115712];

    const int tid  = threadIdx.x;
    const int lane = tid & 63;
    const int wave = tid >> 6;
    const int wr = wave >> 2;        // 0..1
    const int wc = wave & 3;         // 0..3
    const int slab = blockIdx.x;     // 0..15
    const int tokbase = blockIdx.y * BM;

    // per-wave staging sources: slot s = wave*64+lane -> (row = s>>2, koct = s&3)
    const int sA = wave * 64 + lane;
    const int tA = sA >> 2, gA = sA & 3;
    const unsigned short* pAh = xh + (size_t)(tokbase + tA) * DIM + gA * 8;
    const unsigned short* pAl = xl + (size_t)(tokbase + tA) * DIM + gA * 8;
    const int nB = sA >> 2, gB = sA & 3;

    // fragment LDS byte offsets (constant across K steps)
    int offA[4], offB[4];
#pragma unroll
    for (int m = 0; m < 4; ++m)
        offA[m] = (wr * 64 + m * 16 + (lane & 15)) * 64 + (lane >> 4) * 16;
#pragma unroll
    for (int n = 0; n < 4; ++n)
        offB[n] = 16384 + (wc * 64 + n * 16 + (lane & 15)) * 64 + (lane >> 4) * 16;

    float ts[CK]; int ti[CK];
#pragma unroll
    for (int k = 0; k < CK; ++k) { ts[k] = -INFINITY; ti[k] = 0x7fffffff; }
    const int p_sel   = tid >> 7;     // 0..3 (32-col part)
    const int tok_sel = tid & 127;

    float* sel = (float*)(smem + 49152);

#pragma unroll 1
    for (int nc = 0; nc < NCHUNK; ++nc) {
        const int n0 = slab * SLABCOLS + nc * CHUNK;
        const unsigned short* pBh0 = WhT + (size_t)(n0 +       nB) * DIM + gB * 8;
        const unsigned short* pBh1 = WhT + (size_t)(n0 + 128 + nB) * DIM + gB * 8;
        const unsigned short* pBl0 = WlT + (size_t)(n0 +       nB) * DIM + gB * 8;
        const unsigned short* pBl1 = WlT + (size_t)(n0 + 128 + nB) * DIM + gB * 8;

        f32x4 acc[4][4];
        const f32x4 zero = {0.f, 0.f, 0.f, 0.f};
#pragma unroll
        for (int m = 0; m < 4; ++m)
#pragma unroll
            for (int n = 0; n < 4; ++n) acc[m][n] = zero;

        // ---- staging: 6 global_load_lds per wave per K-step ----
        #define STAGE(buf, kk) do {                                              \
            const int koff = (kk) * BK;                                          \
            unsigned ldsb = (unsigned)(buf) * 49152u + (unsigned)wave * 1024u;   \
            gll16(pAh + koff, smem + ldsb);                                      \
            gll16(pAl + koff, smem + ldsb + 8192);                               \
            gll16(pBh0 + koff, smem + ldsb + 16384);                             \
            gll16(pBh1 + koff, smem + ldsb + 16384 + 8192);                      \
            gll16(pBl0 + koff, smem + ldsb + 32768);                             \
            gll16(pBl1 + koff, smem + ldsb + 32768 + 8192);                      \
        } while (0)

        STAGE(0, 0);
        __syncthreads();

#pragma unroll 1
        for (int kk = 0; kk < KSTEPS; ++kk) {
            const int cur = kk & 1;
            if (kk + 1 < KSTEPS) STAGE(cur ^ 1, kk + 1);
            const unsigned char* b = smem + cur * 49152;
            f16x8 Ah[4], Al[4], Bh[4], Bl[4];
#pragma unroll
            for (int m = 0; m < 4; ++m) {
                Ah[m] = *(const f16x8*)(b + offA[m]);
                Al[m] = *(const f16x8*)(b + 8192 + offA[m]);
            }
#pragma unroll
            for (int n = 0; n < 4; ++n) {
                Bh[n] = *(const f16x8*)(b + offB[n]);
                Bl[n] = *(const f16x8*)(b + 16384 + offB[n]);
            }
#pragma unroll
            for (int m = 0; m < 4; ++m)
#pragma unroll
                for (int n = 0; n < 4; ++n) {
                    acc[m][n] = __builtin_amdgcn_mfma_f32_16x16x32_f16(Ah[m], Bh[n], acc[m][n], 0, 0, 0);
                    acc[m][n] = __builtin_amdgcn_mfma_f32_16x16x32_f16(Ah[m], Bl[n], acc[m][n], 0, 0, 0);
                    acc[m][n] = __builtin_amdgcn_mfma_f32_16x16x32_f16(Al[m], Bh[n], acc[m][n], 0, 0, 0);
                }
            __syncthreads();
        }
        #undef STAGE

        // ---- selection on this 256-col chunk, two 128-col halves ----
#pragma unroll 1
        for (int h = 0; h < 2; ++h) {
            if ((wc >> 1) == h) {
#pragma unroll
                for (int m = 0; m < 4; ++m)
#pragma unroll
                    for (int n = 0; n < 4; ++n) {
                        int col = (wc & 1) * 64 + n * 16 + (lane & 15);
                        int row = wr * 64 + m * 16 + (lane >> 4) * 4;
#pragma unroll
                        for (int r = 0; r < 4; ++r)
                            sel[(row + r) * 130 + col] = acc[m][n][r];
                    }
            }
            __syncthreads();
            const float* rowp = sel + tok_sel * 130;
            const int cbase = p_sel * 32;
            const int ibase = n0 + h * 128 + cbase;
#pragma unroll 1
            for (int j = 0; j < 32; ++j) {
                float v = rowp[cbase + j];
                if (v > ts[CK - 1]) {       // strict: later (higher idx) loses ties
                    float cv = v; int ci = ibase + j;
#pragma unroll
                    for (int k = 0; k < CK; ++k) {
                        bool g = cv > ts[k];
                        float os = ts[k]; int oi = ti[k];
                        ts[k] = g ? cv : os; ti[k] = g ? ci : oi;
                        cv = g ? os : cv;   ci = g ? oi : ci;
                    }
                }
            }
            __syncthreads();
        }
    }

    // ---- merge 4 per-part sorted lists per token -> top-20 for this slab ----
    __syncthreads();
    float* Ls = (float*)smem;
    int*   Li = (int*)(smem + 40960);
#pragma unroll
    for (int k = 0; k < CK; ++k) {
        Ls[tid * CK + k] = ts[k];
        Li[tid * CK + k] = ti[k];
    }
    __syncthreads();
    if (tid < BM) {
        int h0 = 0, h1 = 0, h2 = 0, h3 = 0;
        const size_t ob = ((size_t)(tokbase + tid) * SLABS + slab) * CK;
#pragma unroll 1
        for (int k = 0; k < CK; ++k) {
            float s0 = Ls[(      tid) * CK + h0]; int i0 = Li[(      tid) * CK + h0];
            float s1 = Ls[(128 + tid) * CK + h1]; int i1 = Li[(128 + tid) * CK + h1];
            float s2 = Ls[(256 + tid) * CK + h2]; int i2 = Li[(256 + tid) * CK + h2];
            float s3 = Ls[(384 + tid) * CK + h3]; int i3 = Li[(384 + tid) * CK + h3];
            float bs = s0; int bi = i0; int bp = 0;
            if (s1 > bs || (s1 == bs && i1 < bi)) { bs = s1; bi = i1; bp = 1; }
            if (s2 > bs || (s2 == bs && i2 < bi)) { bs = s2; bi = i2; bp = 2; }
            if (s3 > bs || (s3 == bs && i3 < bi)) { bs = s3; bi = i3; bp = 3; }
            part_s[ob + k] = bs; part_i[ob + k] = bi;
            if      (bp == 0) ++h0;
            else if (bp == 1) ++h1;
            else if (bp == 2) ++h2;
            else              ++h3;
        }
    }
}

// ---------------------------------------------------------------------------
// Fallback K1 (round-1, f32 VALU): proven correct path if ws is too small.
// ---------------------------------------------------------------------------
__global__ __launch_bounds__(256, 2)
void k1_router_f32(const float* __restrict__ x, const float* __restrict__ Wr,
                   float* __restrict__ part_s, int* __restrict__ part_i)
{
    __shared__ float smem[64][257];
    const int tid     = threadIdx.x;
    const int tokbase = blockIdx.x * 64;
    const int colbase = blockIdx.y * 8192;
    const int mytok   = tid & 63;
    const int mypart  = tid >> 6;

    float ts[CK]; int ti[CK];
#pragma unroll
    for (int k = 0; k < CK; ++k) { ts[k] = -INFINITY; ti[k] = 0x7fffffff; }

#pragma unroll 1
    for (int cg = 0; cg < 32; ++cg) {
        const int n = colbase + cg * 256 + tid;
        float acc[64];
#pragma unroll
        for (int t = 0; t < 64; ++t) acc[t] = 0.0f;
#pragma unroll 1
        for (int dc = 0; dc < DIM; dc += 8) {
            float w[8];
#pragma unroll
            for (int i = 0; i < 8; ++i)
                w[i] = Wr[(size_t)(dc + i) * NCOL + n];
#pragma unroll
            for (int t = 0; t < 64; ++t) {
                const float* xr = x + (size_t)(tokbase + t) * DIM + dc;
#pragma unroll
                for (int i = 0; i < 8; ++i)
                    acc[t] = fmaf(xr[i], w[i], acc[t]);
            }
        }
        __syncthreads();
#pragma unroll
        for (int t = 0; t < 64; ++t) smem[t][tid] = acc[t];
        __syncthreads();
        const int jbase = mypart * 64;
#pragma unroll 1
        for (int j = 0; j < 64; ++j) {
            float v = smem[mytok][jbase + j];
            if (v > ts[CK - 1]) {
                float cv = v; int ci = colbase + cg * 256 + jbase + j;
#pragma unroll
                for (int k = 0; k < CK; ++k) {
                    bool g = cv > ts[k];
                    float os = ts[k]; int oi = ti[k];
                    ts[k] = g ? cv : os; ti[k] = g ? ci : oi;
                    cv = g ? os : cv;   ci = g ? oi : ci;
                }
            }
        }
    }
    __syncthreads();
    float* Ls = &smem[0][0];
    int*   Li = (int*)(Ls + 256 * CK);
#pragma unroll
    for (int k = 0; k < CK; ++k) { Ls[tid * CK + k] = ts[k]; Li[tid * CK + k] = ti[k]; }
    __syncthreads();
    if (tid < 64) {
        const int tok = tid;
        int h0 = 0, h1 = 0, h2 = 0, h3 = 0;
        const size_t ob = ((size_t)(tokbase + tok) * 8 + blockIdx.y) * CK;
#pragma unroll 1
        for (int k = 0; k < CK; ++k) {
            float s0 = Ls[(      tok) * CK + h0]; int i0 = Li[(      tok) * CK + h0];
            float s1 = Ls[( 64 + tok) * CK + h1]; int i1 = Li[( 64 + tok) * CK + h1];
            float s2 = Ls[(128 + tok) * CK + h2]; int i2 = Li[(128 + tok) * CK + h2];
            float s3 = Ls[(192 + tok) * CK + h3]; int i3 = Li[(192 + tok) * CK + h3];
            float bs = s0; int bi = i0; int bp = 0;
            if (s1 > bs || (s1 == bs && i1 < bi)) { bs = s1; bi = i1; bp = 1; }
            if (s2 > bs || (s2 == bs && i2 < bi)) { bs = s2; bi = i2; bp = 2; }
            if (s3 > bs || (s3 == bs && i3 < bi)) { bs = s3; bi = i3; bp = 3; }
            part_s[ob + k] = bs; part_i[ob + k] = bi;
            if      (bp == 0) ++h0;
            else if (bp == 1) ++h1;
            else if (bp == 2) ++h2;
            else              ++h3;
        }
    }
}

// ---------------------------------------------------------------------------
// K3: per-token final stage (CT slabs x 20 partials).
// ---------------------------------------------------------------------------
template<int CT, int BLK>
__global__ __launch_bounds__(BLK)
void k3_fine(const float* __restrict__ x, const float* __restrict__ Wenc,
             const float* __restrict__ Kall, const float* __restrict__ Vall,
             const float* __restrict__ part_s, const int* __restrict__ part_i,
             float* __restrict__ out)
{
    const int tok = blockIdx.x;
    const int tid = threadIdx.x;

    __shared__ float xs[DIM];
    __shared__ float qs[RANK];
    __shared__ float ls[CT * CK];
    __shared__ int   li[CT * CK];
    __shared__ int   cand[CK];
    __shared__ float fsc[CK];
    __shared__ float fss[FK];
    __shared__ int   fgi[FK];
    __shared__ float fw[FK];

    if (tid < DIM / 4)
        ((float4*)xs)[tid] = ((const float4*)(x + (size_t)tok * DIM))[tid];
    for (int i = tid; i < CT * CK; i += BLK) {
        ls[i] = part_s[(size_t)tok * (CT * CK) + i];
        li[i] = part_i[(size_t)tok * (CT * CK) + i];
    }
    __syncthreads();

    if (tid < CT * CK) {
        float s = ls[tid]; int idx = li[tid];
        int r = 0;
        for (int e = 0; e < CT * CK; ++e) {
            float s2 = ls[e]; int i2 = li[e];
            r += (s2 > s) || (s2 == s && i2 < idx);
        }
        if (r < CK) cand[r] = idx;
    }
    __syncthreads();

    if (tid < RANK) {
        float q = 0.0f;
#pragma unroll 8
        for (int d = 0; d < DIM; ++d)
            q = fmaf(xs[d], Wenc[(size_t)d * RANK + tid], q);
        qs[tid] = q;
    }
    __syncthreads();

    if (tid < CK) {
        const float* Kr = Kall + (size_t)cand[tid] * RANK;
        float s = 0.0f;
#pragma unroll 8
        for (int r = 0; r < RANK; ++r) s = fmaf(qs[r], Kr[r], s);
        fsc[tid] = s * 0.08838834764831845f;   // 1/sqrt(128)
    }
    __syncthreads();

    if (tid < CK) {
        float s = fsc[tid]; int r = 0;
        for (int e = 0; e < CK; ++e)
            r += (fsc[e] > s) || (fsc[e] == s && e < tid);
        if (r < FK) { fss[r] = s; fgi[r] = cand[tid]; }
    }
    __syncthreads();

    if (tid == 0) {
        float m = fss[0];
#pragma unroll
        for (int k = 1; k < FK; ++k) m = fmaxf(m, fss[k]);
        float w[FK]; float sum = 0.0f;
#pragma unroll
        for (int k = 0; k < FK; ++k) { w[k] = expf(fss[k] - m); sum += w[k]; }
        float inv = 1.0f / sum;
#pragma unroll
        for (int k = 0; k < FK; ++k) fw[k] = w[k] * inv;
    }
    __syncthreads();

    for (int d = tid; d < DIM; d += BLK) {
        float o = 0.0f;
#pragma unroll
        for (int f = 0; f < FK; ++f)
            o = fmaf(fw[f], Vall[(size_t)fgi[f] * DIM + d], o);
        out[(size_t)tok * DIM + d] = o;
    }
}

extern "C" void kernel_launch(void* const* d_in, const int* in_sizes, int n_in,
                              void* d_out, int out_size, void* d_ws, size_t ws_size,
                              hipStream_t stream)
{
    (void)in_sizes; (void)n_in; (void)out_size;
    const float* x    = (const float*)d_in[0];
    const float* Wr   = (const float*)d_in[1];
    const float* Wenc = (const float*)d_in[2];
    const float* Kall = (const float*)d_in[3];
    const float* Vall = (const float*)d_in[4];
    float* out = (float*)d_out;

    const size_t off_ps = 0;
    const size_t off_pi = off_ps + (size_t)NTOK * SLABS * CK * 4;
    const size_t off_xh = off_pi + (size_t)NTOK * SLABS * CK * 4;
    const size_t off_xl = off_xh + (size_t)NTOK * DIM * 2;
    const size_t off_wh = off_xl + (size_t)NTOK * DIM * 2;
    const size_t off_wl = off_wh + (size_t)NCOL * DIM * 2;
    const size_t REQ    = off_wl + (size_t)NCOL * DIM * 2;   // ~282 MiB

    if (ws_size >= REQ) {
        float* part_s = (float*)((char*)d_ws + off_ps);
        int*   part_i = (int*)((char*)d_ws + off_pi);
        unsigned short* xh  = (unsigned short*)((char*)d_ws + off_xh);
        unsigned short* xl  = (unsigned short*)((char*)d_ws + off_xl);
        unsigned short* WhT = (unsigned short*)((char*)d_ws + off_wh);
        unsigned short* WlT = (unsigned short*)((char*)d_ws + off_wl);

        k0_convx<<<NTOK * DIM / 1024, 256, 0, stream>>>(x, xh, xl);
        k0_convw<<<dim3(DIM / 64, NCOL / 64), 256, 0, stream>>>(Wr, WhT, WlT);
        k1_mfma<<<dim3(SLABS, NTOK / BM), 512, 0, stream>>>(xh, xl, WhT, WlT, part_s, part_i);
        k3_fine<SLABS, 384><<<NTOK, 384, 0, stream>>>(x, Wenc, Kall, Vall, part_s, part_i, out);
    } else {
        float* part_s = (float*)d_ws;
        int*   part_i = (int*)d_ws + (size_t)NTOK * 8 * CK;
        k1_router_f32<<<dim3(NTOK / 64, 8), 256, 0, stream>>>(x, Wr, part_s, part_i);
        k3_fine<8, 256><<<NTOK, 256, 0, stream>>>(x, Wenc, Kall, Vall, part_s, part_i, out);
    }
}

// Round 3
// 1937.108 us; speedup vs baseline: 13.2840x; 1.4260x over previous
//
#include <hip/hip_runtime.h>
#include <math.h>
#include <stdint.h>

#define NTOK 4096
#define DIM  1024
#define NCOL 65536
#define RANK 128
#define CK 20
#define FK 10

// ---- Path A (MFMA) geometry ----
#define SLABS 16
#define SLABCOLS (NCOL / SLABS)      // 4096
#define BM 128
#define BN 512
#define BK 32
#define NCHUNK (SLABCOLS / BN)       // 8
#define KSTEPS (DIM / BK)            // 32
#define CKS 12                       // per-slab list length
#define NPART (SLABS * CKS)          // 192
#define POOL 32

typedef _Float16 f16;
typedef __attribute__((ext_vector_type(8))) _Float16 f16x8;
typedef __attribute__((ext_vector_type(4))) float f32x4;

__device__ __forceinline__ void f32_split(float v, unsigned short& h, unsigned short& l) {
    f16 hh = (f16)v;
    float r = v - (float)hh;
    f16 ll = (f16)r;
    h = __builtin_bit_cast(unsigned short, hh);
    l = __builtin_bit_cast(unsigned short, ll);
}

__device__ __forceinline__ void gll16(const void* src, void* ldsdst) {
    __builtin_amdgcn_global_load_lds(
        (__attribute__((address_space(1))) unsigned int*)src,
        (__attribute__((address_space(3))) unsigned int*)ldsdst, 16, 0, 0);
}

#define WAITVM_(n) asm volatile("s_waitcnt vmcnt(" #n ")" ::: "memory")
#define WAITLGKM0  asm volatile("s_waitcnt lgkmcnt(0)" ::: "memory")

// ---------------------------------------------------------------------------
// K0x: x -> f16 hi plane only (A operand), layout [t][k]
// ---------------------------------------------------------------------------
__global__ __launch_bounds__(256)
void k0_convx(const float* __restrict__ x, unsigned short* __restrict__ xh)
{
    int i = blockIdx.x * 256 + threadIdx.x;   // float4 index
    float4 v = ((const float4*)x)[i];
    ushort4 h; unsigned short dummy;
    f32_split(v.x, h.x, dummy); f32_split(v.y, h.y, dummy);
    f32_split(v.z, h.z, dummy); f32_split(v.w, h.w, dummy);
    ((ushort4*)xh)[i] = h;
}

// ---------------------------------------------------------------------------
// K0w: W[k][n] f32 -> WhT[n][k], WlT[n][k]  (f16 bits, scaled x1024), 64x64 tiles
// ---------------------------------------------------------------------------
__global__ __launch_bounds__(256)
void k0_convw(const float* __restrict__ W, unsigned short* __restrict__ WhT,
              unsigned short* __restrict__ WlT)
{
    __shared__ float t[64][65];
    const int tid = threadIdx.x;
    const int k0 = blockIdx.x * 64;
    const int n0 = blockIdx.y * 64;
#pragma unroll
    for (int i = 0; i < 16; ++i) {
        int idx = i * 256 + tid;
        int r = idx >> 6, c = idx & 63;
        t[r][c] = W[(size_t)(k0 + r) * NCOL + n0 + c];
    }
    __syncthreads();
#pragma unroll
    for (int i = 0; i < 8; ++i) {
        int idx = i * 256 + tid;
        int n = idx >> 5, kp = idx & 31;
        float a = t[2 * kp][n]     * 1024.0f;
        float b = t[2 * kp + 1][n] * 1024.0f;
        unsigned short ah, al, bh, bl;
        f32_split(a, ah, al);
        f32_split(b, bh, bl);
        unsigned int wh = (unsigned)ah | ((unsigned)bh << 16);
        unsigned int wl = (unsigned)al | ((unsigned)bl << 16);
        size_t row = (size_t)(n0 + n) * DIM + k0;
        *(unsigned int*)(WhT + row + 2 * kp) = wh;
        *(unsigned int*)(WlT + row + 2 * kp) = wl;
    }
}

// ---------------------------------------------------------------------------
// K1: single-pass f16 MFMA approx logits + fused per-(token, slab) top-12.
// 512 thr (8 waves, 2x4), tile 128 tok x 512 cols/chunk, BK=32.
// 3 staging buffers, counted vmcnt(10), raw s_barrier (no vmcnt(0) in loop).
// ---------------------------------------------------------------------------
__global__ __launch_bounds__(512, 2)
void k1_mfma(const unsigned short* __restrict__ xh,
             const unsigned short* __restrict__ WhT,
             float* __restrict__ part_s, int* __restrict__ part_i)
{
    // 3 staging buffers @ b*40960: A[128][32]f16 (8192B) + B[512][32]f16 (32768B)
    // sel f32[128][65] @ 122880 (33280B). total 156160 <= 160KB.
    __shared__ __align__(16) unsigned char smem[156160];

    const int tid  = threadIdx.x;
    const int lane = tid & 63;
    const int wave = tid >> 6;
    const int wr = wave >> 2;        // 0..1 : 64-row half
    const int wc = wave & 3;         // 0..3 : 128-col group
    const int slab = blockIdx.x;     // 0..15
    const int tokbase = blockIdx.y * BM;

    const int srow = tid >> 2;       // staging row 0..127
    const int soct = tid & 3;        // staging k-octet
    const unsigned short* pA = xh + (size_t)(tokbase + srow) * DIM + soct * 8;

    int offA[4], offB[8];
#pragma unroll
    for (int m = 0; m < 4; ++m)
        offA[m] = (wr * 64 + m * 16 + (lane & 15)) * 64 + (lane >> 4) * 16;
#pragma unroll
    for (int n = 0; n < 8; ++n)
        offB[n] = 8192 + (wc * 128 + n * 16 + (lane & 15)) * 64 + (lane >> 4) * 16;

    float ts[CKS]; int ti[CKS];
#pragma unroll
    for (int k = 0; k < CKS; ++k) { ts[k] = -INFINITY; ti[k] = 0x7fffffff; }
    const int tok_sel = tid >> 2;    // 0..127
    const int part    = tid & 3;     // 16-col sub-part within 64-col slice

    float* sel = (float*)(smem + 122880);

#pragma unroll 1
    for (int nc = 0; nc < NCHUNK; ++nc) {
        const int n0 = slab * SLABCOLS + nc * BN;
        const unsigned short* pB = WhT + (size_t)(n0 + srow) * DIM + soct * 8;

        f32x4 acc[4][8];
        const f32x4 zero = {0.f, 0.f, 0.f, 0.f};
#pragma unroll
        for (int m = 0; m < 4; ++m)
#pragma unroll
            for (int n = 0; n < 8; ++n) acc[m][n] = zero;

        // 5 global_load_lds per thread per K-step (1 A + 4 B)
        #define STAGE(buf, kk) do {                                             \
            unsigned b_ = (unsigned)(buf) * 40960u + (unsigned)wave * 1024u;    \
            gll16(pA + (size_t)(kk) * BK, smem + b_);                           \
            gll16(pB + (size_t)(kk) * BK,                 smem + b_ + 8192);    \
            gll16(pB + (size_t)128 * DIM + (kk) * BK,     smem + b_ + 16384);   \
            gll16(pB + (size_t)256 * DIM + (kk) * BK,     smem + b_ + 24576);   \
            gll16(pB + (size_t)384 * DIM + (kk) * BK,     smem + b_ + 32768);   \
        } while (0)

        STAGE(0, 0);
        STAGE(1, 1);

#pragma unroll 1
        for (int kk = 0; kk < KSTEPS; ++kk) {
            if (kk < KSTEPS - 2) {
                STAGE((kk + 2) % 3, kk + 2);
                WAITVM_(10);                 // stage kk complete; kk+1,kk+2 in flight
            } else if (kk == KSTEPS - 2) {
                WAITVM_(5);
            } else {
                WAITVM_(0);
            }
            __builtin_amdgcn_s_barrier();

            const unsigned char* bp = smem + (unsigned)(kk % 3) * 40960u;
            f16x8 Af[4], Bf[8];
#pragma unroll
            for (int m = 0; m < 4; ++m) Af[m] = *(const f16x8*)(bp + offA[m]);
#pragma unroll
            for (int n = 0; n < 8; ++n) Bf[n] = *(const f16x8*)(bp + offB[n]);
#pragma unroll
            for (int m = 0; m < 4; ++m)
#pragma unroll
                for (int n = 0; n < 8; ++n)
                    acc[m][n] = __builtin_amdgcn_mfma_f32_16x16x32_f16(Af[m], Bf[n], acc[m][n], 0, 0, 0);

            WAITLGKM0;                       // my frag reads done before others overwrite
            __builtin_amdgcn_s_barrier();
        }
        #undef STAGE

        // ---- selection: 8 phases of 64 cols (conflict-free stride 65) ----
#pragma unroll 1
        for (int p = 0; p < 8; ++p) {
            if (wc == (p >> 1)) {
                const int nb = (p & 1) * 4;
#pragma unroll
                for (int m = 0; m < 4; ++m)
#pragma unroll
                    for (int nn = 0; nn < 4; ++nn) {
                        const int col = nn * 16 + (lane & 15);
                        const int row = wr * 64 + m * 16 + (lane >> 4) * 4;
#pragma unroll
                        for (int r = 0; r < 4; ++r)
                            sel[(row + r) * 65 + col] = acc[m][nb + nn][r];
                    }
            }
            __syncthreads();
            {
                const float* rp = sel + tok_sel * 65 + part * 16;
                const int ibase = n0 + (p >> 1) * 128 + (p & 1) * 64 + part * 16;
#pragma unroll 1
                for (int j = 0; j < 16; ++j) {
                    float v = rp[j];
                    if (v > ts[CKS - 1]) {     // strict: later (higher idx) loses ties
                        float cv = v; int ci = ibase + j;
#pragma unroll
                        for (int k = 0; k < CKS; ++k) {
                            bool g = cv > ts[k];
                            float os = ts[k]; int oi = ti[k];
                            ts[k] = g ? cv : os; ti[k] = g ? ci : oi;
                            cv = g ? os : cv;   ci = g ? oi : ci;
                        }
                    }
                }
            }
            __syncthreads();
        }
    }

    // ---- merge the 4 per-part lists per token -> slab top-12 ----
    __syncthreads();
    float* Ls = (float*)smem;                 // 512*12*4 = 24576
    int*   Li = (int*)(smem + 24576);
#pragma unroll
    for (int k = 0; k < CKS; ++k) {
        Ls[tid * CKS + k] = ts[k];
        Li[tid * CKS + k] = ti[k];
    }
    __syncthreads();
    if (tid < BM) {
        const int b0 = (tid * 4 + 0) * CKS, b1 = (tid * 4 + 1) * CKS;
        const int b2 = (tid * 4 + 2) * CKS, b3 = (tid * 4 + 3) * CKS;
        int h0 = 0, h1 = 0, h2 = 0, h3 = 0;
        const size_t ob = ((size_t)(tokbase + tid) * SLABS + slab) * CKS;
#pragma unroll 1
        for (int k = 0; k < CKS; ++k) {
            float s0 = Ls[b0 + h0]; int i0 = Li[b0 + h0];
            float s1 = Ls[b1 + h1]; int i1 = Li[b1 + h1];
            float s2 = Ls[b2 + h2]; int i2 = Li[b2 + h2];
            float s3 = Ls[b3 + h3]; int i3 = Li[b3 + h3];
            float bs = s0; int bi = i0; int bp = 0;
            if (s1 > bs || (s1 == bs && i1 < bi)) { bs = s1; bi = i1; bp = 1; }
            if (s2 > bs || (s2 == bs && i2 < bi)) { bs = s2; bi = i2; bp = 2; }
            if (s3 > bs || (s3 == bs && i3 < bi)) { bs = s3; bi = i3; bp = 3; }
            part_s[ob + k] = bs; part_i[ob + k] = bi;
            if      (bp == 0) ++h0;
            else if (bp == 1) ++h1;
            else if (bp == 2) ++h2;
            else              ++h3;
        }
    }
}

// ---------------------------------------------------------------------------
// K3: merge 192 approx partials -> approx top-32 pool -> exact rescore
// (f32 x, split-f16 W reconstruction) -> exact top-20 -> fine stage.
// ---------------------------------------------------------------------------
__global__ __launch_bounds__(256)
void k3_fine(const float* __restrict__ x, const float* __restrict__ Wenc,
             const float* __restrict__ Kall, const float* __restrict__ Vall,
             const unsigned short* __restrict__ WhT, const unsigned short* __restrict__ WlT,
             const float* __restrict__ part_s, const int* __restrict__ part_i,
             float* __restrict__ out)
{
    const int tok = blockIdx.x;
    const int tid = threadIdx.x;

    __shared__ float xs[DIM];
    __shared__ float qs[RANK];
    __shared__ float ls[NPART];
    __shared__ int   li[NPART];
    __shared__ int   pool[POOL];
    __shared__ float resc[POOL];
    __shared__ int   cand[CK];
    __shared__ float fsc[CK];
    __shared__ float fss[FK];
    __shared__ int   fgi[FK];
    __shared__ float fw[FK];

    ((float4*)xs)[tid] = ((const float4*)(x + (size_t)tok * DIM))[tid];
    if (tid < NPART) {
        ls[tid] = part_s[(size_t)tok * NPART + tid];
        li[tid] = part_i[(size_t)tok * NPART + tid];
    }
    __syncthreads();

    // approx top-32 of 192 via lex rank (idx distinct -> unique ranks)
    if (tid < NPART) {
        float s = ls[tid]; int idx = li[tid];
        int r = 0;
        for (int e = 0; e < NPART; ++e) {
            float s2 = ls[e]; int i2 = li[e];
            r += (s2 > s) || (s2 == s && i2 < idx);
        }
        if (r < POOL) pool[r] = idx;
    }
    __syncthreads();

    // exact rescore of 32 pooled candidates: 8 threads per candidate
    {
        const int c = tid >> 3, oct = tid & 7;
        const int idx = pool[c];
        const ushort4* ph = (const ushort4*)(WhT + (size_t)idx * DIM + oct * 128);
        const ushort4* pl = (const ushort4*)(WlT + (size_t)idx * DIM + oct * 128);
        const float* xp = xs + oct * 128;
        float a = 0.0f;
#pragma unroll 4
        for (int j = 0; j < 32; ++j) {
            ushort4 hv = ph[j], lv = pl[j];
            a = fmaf(xp[j*4+0], (float)__builtin_bit_cast(f16, hv.x) + (float)__builtin_bit_cast(f16, lv.x), a);
            a = fmaf(xp[j*4+1], (float)__builtin_bit_cast(f16, hv.y) + (float)__builtin_bit_cast(f16, lv.y), a);
            a = fmaf(xp[j*4+2], (float)__builtin_bit_cast(f16, hv.z) + (float)__builtin_bit_cast(f16, lv.z), a);
            a = fmaf(xp[j*4+3], (float)__builtin_bit_cast(f16, hv.w) + (float)__builtin_bit_cast(f16, lv.w), a);
        }
        a += __shfl_down(a, 4, 8);
        a += __shfl_down(a, 2, 8);
        a += __shfl_down(a, 1, 8);
        if (oct == 0) resc[c] = a * (1.0f / 1024.0f);   // undo x1024 W scale (exact)
    }
    __syncthreads();

    // exact top-20 of 32 rescored (lex: score desc, idx asc)
    if (tid < POOL) {
        float s = resc[tid]; int idx = pool[tid];
        int r = 0;
        for (int e = 0; e < POOL; ++e)
            r += (resc[e] > s) || (resc[e] == s && pool[e] < idx);
        if (r < CK) cand[r] = idx;
    }
    __syncthreads();

    // query = x . W_enc
    if (tid < RANK) {
        float q = 0.0f;
#pragma unroll 8
        for (int d = 0; d < DIM; ++d)
            q = fmaf(xs[d], Wenc[(size_t)d * RANK + tid], q);
        qs[tid] = q;
    }
    __syncthreads();

    if (tid < CK) {
        const float* Kr = Kall + (size_t)cand[tid] * RANK;
        float s = 0.0f;
#pragma unroll 8
        for (int r = 0; r < RANK; ++r) s = fmaf(qs[r], Kr[r], s);
        fsc[tid] = s * 0.08838834764831845f;   // 1/sqrt(128)
    }
    __syncthreads();

    if (tid < CK) {
        float s = fsc[tid]; int r = 0;
        for (int e = 0; e < CK; ++e)
            r += (fsc[e] > s) || (fsc[e] == s && e < tid);
        if (r < FK) { fss[r] = s; fgi[r] = cand[tid]; }
    }
    __syncthreads();

    if (tid == 0) {
        float m = fss[0];
#pragma unroll
        for (int k = 1; k < FK; ++k) m = fmaxf(m, fss[k]);
        float w[FK]; float sum = 0.0f;
#pragma unroll
        for (int k = 0; k < FK; ++k) { w[k] = expf(fss[k] - m); sum += w[k]; }
        float inv = 1.0f / sum;
#pragma unroll
        for (int k = 0; k < FK; ++k) fw[k] = w[k] * inv;
    }
    __syncthreads();

#pragma unroll
    for (int jj = 0; jj < DIM / 256; ++jj) {
        const int d = tid + jj * 256;
        float o = 0.0f;
#pragma unroll
        for (int f = 0; f < FK; ++f)
            o = fmaf(fw[f], Vall[(size_t)fgi[f] * DIM + d], o);
        out[(size_t)tok * DIM + d] = o;
    }
}

// ---------------------------------------------------------------------------
// Fallback path (round-1, f32 VALU): proven correct if ws is too small.
// ---------------------------------------------------------------------------
__global__ __launch_bounds__(256, 2)
void k1_router_f32(const float* __restrict__ x, const float* __restrict__ Wr,
                   float* __restrict__ part_s, int* __restrict__ part_i)
{
    __shared__ float smem[64][257];
    const int tid     = threadIdx.x;
    const int tokbase = blockIdx.x * 64;
    const int colbase = blockIdx.y * 8192;
    const int mytok   = tid & 63;
    const int mypart  = tid >> 6;

    float ts[CK]; int ti[CK];
#pragma unroll
    for (int k = 0; k < CK; ++k) { ts[k] = -INFINITY; ti[k] = 0x7fffffff; }

#pragma unroll 1
    for (int cg = 0; cg < 32; ++cg) {
        const int n = colbase + cg * 256 + tid;
        float acc[64];
#pragma unroll
        for (int t = 0; t < 64; ++t) acc[t] = 0.0f;
#pragma unroll 1
        for (int dc = 0; dc < DIM; dc += 8) {
            float w[8];
#pragma unroll
            for (int i = 0; i < 8; ++i)
                w[i] = Wr[(size_t)(dc + i) * NCOL + n];
#pragma unroll
            for (int t = 0; t < 64; ++t) {
                const float* xr = x + (size_t)(tokbase + t) * DIM + dc;
#pragma unroll
                for (int i = 0; i < 8; ++i)
                    acc[t] = fmaf(xr[i], w[i], acc[t]);
            }
        }
        __syncthreads();
#pragma unroll
        for (int t = 0; t < 64; ++t) smem[t][tid] = acc[t];
        __syncthreads();
        const int jbase = mypart * 64;
#pragma unroll 1
        for (int j = 0; j < 64; ++j) {
            float v = smem[mytok][jbase + j];
            if (v > ts[CK - 1]) {
                float cv = v; int ci = colbase + cg * 256 + jbase + j;
#pragma unroll
                for (int k = 0; k < CK; ++k) {
                    bool g = cv > ts[k];
                    float os = ts[k]; int oi = ti[k];
                    ts[k] = g ? cv : os; ti[k] = g ? ci : oi;
                    cv = g ? os : cv;   ci = g ? oi : ci;
                }
            }
        }
    }
    __syncthreads();
    float* Ls = &smem[0][0];
    int*   Li = (int*)(Ls + 256 * CK);
#pragma unroll
    for (int k = 0; k < CK; ++k) { Ls[tid * CK + k] = ts[k]; Li[tid * CK + k] = ti[k]; }
    __syncthreads();
    if (tid < 64) {
        const int tok = tid;
        int h0 = 0, h1 = 0, h2 = 0, h3 = 0;
        const size_t ob = ((size_t)(tokbase + tok) * 8 + blockIdx.y) * CK;
#pragma unroll 1
        for (int k = 0; k < CK; ++k) {
            float s0 = Ls[(      tok) * CK + h0]; int i0 = Li[(      tok) * CK + h0];
            float s1 = Ls[( 64 + tok) * CK + h1]; int i1 = Li[( 64 + tok) * CK + h1];
            float s2 = Ls[(128 + tok) * CK + h2]; int i2 = Li[(128 + tok) * CK + h2];
            float s3 = Ls[(192 + tok) * CK + h3]; int i3 = Li[(192 + tok) * CK + h3];
            float bs = s0; int bi = i0; int bp = 0;
            if (s1 > bs || (s1 == bs && i1 < bi)) { bs = s1; bi = i1; bp = 1; }
            if (s2 > bs || (s2 == bs && i2 < bi)) { bs = s2; bi = i2; bp = 2; }
            if (s3 > bs || (s3 == bs && i3 < bi)) { bs = s3; bi = i3; bp = 3; }
            part_s[ob + k] = bs; part_i[ob + k] = bi;
            if      (bp == 0) ++h0;
            else if (bp == 1) ++h1;
            else if (bp == 2) ++h2;
            else              ++h3;
        }
    }
}

template<int CT, int BLK>
__global__ __launch_bounds__(BLK)
void k3_fine_direct(const float* __restrict__ x, const float* __restrict__ Wenc,
                    const float* __restrict__ Kall, const float* __restrict__ Vall,
                    const float* __restrict__ part_s, const int* __restrict__ part_i,
                    float* __restrict__ out)
{
    const int tok = blockIdx.x;
    const int tid = threadIdx.x;

    __shared__ float xs[DIM];
    __shared__ float qs[RANK];
    __shared__ float ls[CT * CK];
    __shared__ int   li[CT * CK];
    __shared__ int   cand[CK];
    __shared__ float fsc[CK];
    __shared__ float fss[FK];
    __shared__ int   fgi[FK];
    __shared__ float fw[FK];

    if (tid < DIM / 4)
        ((float4*)xs)[tid] = ((const float4*)(x + (size_t)tok * DIM))[tid];
    for (int i = tid; i < CT * CK; i += BLK) {
        ls[i] = part_s[(size_t)tok * (CT * CK) + i];
        li[i] = part_i[(size_t)tok * (CT * CK) + i];
    }
    __syncthreads();

    if (tid < CT * CK) {
        float s = ls[tid]; int idx = li[tid];
        int r = 0;
        for (int e = 0; e < CT * CK; ++e) {
            float s2 = ls[e]; int i2 = li[e];
            r += (s2 > s) || (s2 == s && i2 < idx);
        }
        if (r < CK) cand[r] = idx;
    }
    __syncthreads();

    if (tid < RANK) {
        float q = 0.0f;
#pragma unroll 8
        for (int d = 0; d < DIM; ++d)
            q = fmaf(xs[d], Wenc[(size_t)d * RANK + tid], q);
        qs[tid] = q;
    }
    __syncthreads();

    if (tid < CK) {
        const float* Kr = Kall + (size_t)cand[tid] * RANK;
        float s = 0.0f;
#pragma unroll 8
        for (int r = 0; r < RANK; ++r) s = fmaf(qs[r], Kr[r], s);
        fsc[tid] = s * 0.08838834764831845f;
    }
    __syncthreads();

    if (tid < CK) {
        float s = fsc[tid]; int r = 0;
        for (int e = 0; e < CK; ++e)
            r += (fsc[e] > s) || (fsc[e] == s && e < tid);
        if (r < FK) { fss[r] = s; fgi[r] = cand[tid]; }
    }
    __syncthreads();

    if (tid == 0) {
        float m = fss[0];
#pragma unroll
        for (int k = 1; k < FK; ++k) m = fmaxf(m, fss[k]);
        float w[FK]; float sum = 0.0f;
#pragma unroll
        for (int k = 0; k < FK; ++k) { w[k] = expf(fss[k] - m); sum += w[k]; }
        float inv = 1.0f / sum;
#pragma unroll
        for (int k = 0; k < FK; ++k) fw[k] = w[k] * inv;
    }
    __syncthreads();

    for (int d = tid; d < DIM; d += BLK) {
        float o = 0.0f;
#pragma unroll
        for (int f = 0; f < FK; ++f)
            o = fmaf(fw[f], Vall[(size_t)fgi[f] * DIM + d], o);
        out[(size_t)tok * DIM + d] = o;
    }
}

extern "C" void kernel_launch(void* const* d_in, const int* in_sizes, int n_in,
                              void* d_out, int out_size, void* d_ws, size_t ws_size,
                              hipStream_t stream)
{
    (void)in_sizes; (void)n_in; (void)out_size;
    const float* x    = (const float*)d_in[0];
    const float* Wr   = (const float*)d_in[1];
    const float* Wenc = (const float*)d_in[2];
    const float* Kall = (const float*)d_in[3];
    const float* Vall = (const float*)d_in[4];
    float* out = (float*)d_out;

    const size_t off_ps = 0;
    const size_t off_pi = off_ps + (size_t)NTOK * NPART * 4;
    const size_t off_xh = off_pi + (size_t)NTOK * NPART * 4;
    const size_t off_wh = off_xh + (size_t)NTOK * DIM * 2;
    const size_t off_wl = off_wh + (size_t)NCOL * DIM * 2;
    const size_t REQ    = off_wl + (size_t)NCOL * DIM * 2;   // ~270 MiB

    if (ws_size >= REQ) {
        float* part_s = (float*)((char*)d_ws + off_ps);
        int*   part_i = (int*)((char*)d_ws + off_pi);
        unsigned short* xh  = (unsigned short*)((char*)d_ws + off_xh);
        unsigned short* WhT = (unsigned short*)((char*)d_ws + off_wh);
        unsigned short* WlT = (unsigned short*)((char*)d_ws + off_wl);

        k0_convx<<<NTOK * DIM / 1024, 256, 0, stream>>>(x, xh);
        k0_convw<<<dim3(DIM / 64, NCOL / 64), 256, 0, stream>>>(Wr, WhT, WlT);
        k1_mfma<<<dim3(SLABS, NTOK / BM), 512, 0, stream>>>(xh, WhT, part_s, part_i);
        k3_fine<<<NTOK, 256, 0, stream>>>(x, Wenc, Kall, Vall, WhT, WlT, part_s, part_i, out);
    } else {
        float* part_s = (float*)d_ws;
        int*   part_i = (int*)d_ws + (size_t)NTOK * 8 * CK;
        k1_router_f32<<<dim3(NTOK / 64, 8), 256, 0, stream>>>(x, Wr, part_s, part_i);
        k3_fine_direct<8, 256><<<NTOK, 256, 0, stream>>>(x, Wenc, Kall, Vall, part_s, part_i, out);
    }
}

// Round 4
// 1277.334 us; speedup vs baseline: 20.1455x; 1.5165x over previous
//
#include <hip/hip_runtime.h>
#include <math.h>
#include <stdint.h>

#define NTOK 4096
#define DIM  1024
#define NCOL 65536
#define RANK 128
#define CK 20
#define FK 10

// ---- Path A (MFMA) geometry ----
#define SLABS 16
#define SLABCOLS (NCOL / SLABS)      // 4096
#define BM 128
#define BN 256
#define BK 32
#define NCHUNK (SLABCOLS / BN)       // 16
#define KSTEPS (DIM / BK)            // 32
#define CKS 12                       // per-slab list length
#define NPART (SLABS * CKS)          // 192
#define POOL 32
#define BUFSZ 24576                  // A 8KB + B 16KB
#define SELSTRIDE 132

typedef _Float16 f16;
typedef __attribute__((ext_vector_type(8))) _Float16 f16x8;
typedef __attribute__((ext_vector_type(4))) float f32x4;

__device__ __forceinline__ void f32_split(float v, unsigned short& h, unsigned short& l) {
    f16 hh = (f16)v;
    float r = v - (float)hh;
    f16 ll = (f16)r;
    h = __builtin_bit_cast(unsigned short, hh);
    l = __builtin_bit_cast(unsigned short, ll);
}

__device__ __forceinline__ void gll16(const void* src, void* ldsdst) {
    __builtin_amdgcn_global_load_lds(
        (__attribute__((address_space(1))) unsigned int*)src,
        (__attribute__((address_space(3))) unsigned int*)ldsdst, 16, 0, 0);
}

#define WAITVM_(n) asm volatile("s_waitcnt vmcnt(" #n ")" ::: "memory")
#define WAITLGKM0  asm volatile("s_waitcnt lgkmcnt(0)" ::: "memory")

// ---------------------------------------------------------------------------
// K0x: x -> f16 hi plane only (A operand), layout [t][k]
// ---------------------------------------------------------------------------
__global__ __launch_bounds__(256)
void k0_convx(const float* __restrict__ x, unsigned short* __restrict__ xh)
{
    int i = blockIdx.x * 256 + threadIdx.x;   // float4 index
    float4 v = ((const float4*)x)[i];
    ushort4 h; unsigned short dummy;
    f32_split(v.x, h.x, dummy); f32_split(v.y, h.y, dummy);
    f32_split(v.z, h.z, dummy); f32_split(v.w, h.w, dummy);
    ((ushort4*)xh)[i] = h;
}

// ---------------------------------------------------------------------------
// K0w: W[k][n] f32 -> WhT[n][k], WlT[n][k]  (f16 bits, scaled x1024), 64x64 tiles
// ---------------------------------------------------------------------------
__global__ __launch_bounds__(256)
void k0_convw(const float* __restrict__ W, unsigned short* __restrict__ WhT,
              unsigned short* __restrict__ WlT)
{
    __shared__ float t[64][65];
    const int tid = threadIdx.x;
    const int k0 = blockIdx.x * 64;
    const int n0 = blockIdx.y * 64;
#pragma unroll
    for (int i = 0; i < 16; ++i) {
        int idx = i * 256 + tid;
        int r = idx >> 6, c = idx & 63;
        t[r][c] = W[(size_t)(k0 + r) * NCOL + n0 + c];
    }
    __syncthreads();
#pragma unroll
    for (int i = 0; i < 8; ++i) {
        int idx = i * 256 + tid;
        int n = idx >> 5, kp = idx & 31;
        float a = t[2 * kp][n]     * 1024.0f;
        float b = t[2 * kp + 1][n] * 1024.0f;
        unsigned short ah, al, bh, bl;
        f32_split(a, ah, al);
        f32_split(b, bh, bl);
        unsigned int wh = (unsigned)ah | ((unsigned)bh << 16);
        unsigned int wl = (unsigned)al | ((unsigned)bl << 16);
        size_t row = (size_t)(n0 + n) * DIM + k0;
        *(unsigned int*)(WhT + row + 2 * kp) = wh;
        *(unsigned int*)(WlT + row + 2 * kp) = wl;
    }
}

// ---------------------------------------------------------------------------
// K1: single-pass f16 MFMA approx logits + fused per-(token, slab) top-12.
// 512 thr (8 waves, 2x4), tile 128 tok x 256 cols/chunk, BK=32.
// 3 staging buffers (24KB each, XOR-swizzled layout), counted vmcnt,
// 72KB LDS total -> 2 blocks/CU. acc[4][4] -> no spill.
// ---------------------------------------------------------------------------
__global__ __launch_bounds__(512, 4)
void k1_mfma(const unsigned short* __restrict__ xh,
             const unsigned short* __restrict__ WhT,
             float* __restrict__ part_s, int* __restrict__ part_i)
{
    // 3 staging buffers @ b*24576: A[128][32]f16 (8KB) + B[256][32]f16 (16KB)
    // swizzle: LDS (row, slot) holds global k-octet (slot ^ (row&3))
    // sel f32[128][132] @ 0 (67584B) aliases staging (dead during selection)
    // merge lists @ 0 / 24576 after all chunks done
    __shared__ __align__(16) unsigned char smem[73728];

    const int tid  = threadIdx.x;
    const int lane = tid & 63;
    const int wave = tid >> 6;
    const int wr = wave >> 2;        // 0..1 : 64-row half
    const int wc = wave & 3;         // 0..3 : 64-col group
    const int slab = blockIdx.x;     // 0..15
    const int tokbase = blockIdx.y * BM;

    // staging source (pre-swizzled): thread covers (row = wave*16 + lane>>2)
    const int srow = wave * 16 + (lane >> 2);
    const int soct = (lane & 3) ^ (srow & 3);
    const unsigned short* pA = xh + (size_t)(tokbase + srow) * DIM + soct * 8;

    // frag base offsets (XOR-swizzled read): row&3 == lane&3 for both A and B
    const int xorj = (((lane >> 4) ^ (lane & 3)) << 4);
    const int offA0 =        (wr * 64 + (lane & 15)) * 64 + xorj;
    const int offB0 = 8192 + (wc * 64 + (lane & 15)) * 64 + xorj;

    float ts[CKS]; int ti[CKS];
#pragma unroll
    for (int k = 0; k < CKS; ++k) { ts[k] = -INFINITY; ti[k] = 0x7fffffff; }

    float* sel = (float*)smem;

#pragma unroll 1
    for (int nc = 0; nc < NCHUNK; ++nc) {
        const int n0 = slab * SLABCOLS + nc * BN;
        const unsigned short* pB = WhT + (size_t)(n0 + srow) * DIM + soct * 8;

        f32x4 acc[4][4];
        const f32x4 zero = {0.f, 0.f, 0.f, 0.f};
#pragma unroll
        for (int m = 0; m < 4; ++m)
#pragma unroll
            for (int n = 0; n < 4; ++n) acc[m][n] = zero;

        // 3 global_load_lds per thread per K-step (1 A + 2 B)
        #define STAGE(buf, kk) do {                                             \
            unsigned b_ = (unsigned)(buf) * 24576u + (unsigned)wave * 1024u;    \
            gll16(pA + (size_t)(kk) * BK,                 smem + b_);           \
            gll16(pB + (size_t)(kk) * BK,                 smem + b_ + 8192);    \
            gll16(pB + (size_t)128 * DIM + (kk) * BK,     smem + b_ + 16384);   \
        } while (0)

        STAGE(0, 0);
        STAGE(1, 1);

#pragma unroll 1
        for (int kk = 0; kk < KSTEPS; ++kk) {
            if (kk < KSTEPS - 2) {
                STAGE((kk + 2) % 3, kk + 2);
                WAITVM_(6);                  // stage kk complete; kk+1,kk+2 in flight
            } else if (kk == KSTEPS - 2) {
                WAITVM_(3);
            } else {
                WAITVM_(0);
            }
            __builtin_amdgcn_s_barrier();

            const unsigned char* bp = smem + (unsigned)(kk % 3) * 24576u;
            f16x8 Af[4];
#pragma unroll
            for (int m = 0; m < 4; ++m) Af[m] = *(const f16x8*)(bp + offA0 + m * 1024);
#pragma unroll
            for (int n = 0; n < 4; ++n) {
                f16x8 Bf = *(const f16x8*)(bp + offB0 + n * 1024);
#pragma unroll
                for (int m = 0; m < 4; ++m)
                    acc[m][n] = __builtin_amdgcn_mfma_f32_16x16x32_f16(Af[m], Bf, acc[m][n], 0, 0, 0);
            }

            WAITLGKM0;                       // my frag reads done before others overwrite
            __builtin_amdgcn_s_barrier();
        }
        #undef STAGE

        // ---- selection: 2 phases of 128 cols; sel stride 132 (2-way max) ----
#pragma unroll 1
        for (int p = 0; p < 2; ++p) {
            if ((wc >> 1) == p) {
                const int colb = (wc & 1) * 64;
#pragma unroll
                for (int m = 0; m < 4; ++m)
#pragma unroll
                    for (int n = 0; n < 4; ++n) {
                        const int col = colb + n * 16 + (lane & 15);
                        const int row = wr * 64 + m * 16 + (lane >> 4) * 4;
#pragma unroll
                        for (int r = 0; r < 4; ++r)
                            sel[(row + r) * SELSTRIDE + col] = acc[m][n][r];
                    }
            }
            __syncthreads();
            {
                // thread scans cols part, part+4, ..., part+124 of its token
                const int part = tid & 3;
                const float* rp = sel + (tid >> 2) * SELSTRIDE + part;
                const int ibase = n0 + p * 128 + part;
#pragma unroll 1
                for (int j = 0; j < 32; ++j) {
                    float v = rp[4 * j];
                    if (v > ts[CKS - 1]) {     // strict: later (higher idx) loses ties
                        float cv = v; int ci = ibase + 4 * j;
#pragma unroll
                        for (int k = 0; k < CKS; ++k) {
                            bool g = cv > ts[k];
                            float os = ts[k]; int oi = ti[k];
                            ts[k] = g ? cv : os; ti[k] = g ? ci : oi;
                            cv = g ? os : cv;   ci = g ? oi : ci;
                        }
                    }
                }
            }
            __syncthreads();
        }
    }

    // ---- merge the 4 per-part lists per token -> slab top-12 ----
    float* Ls = (float*)smem;                 // 512*12*4 = 24576
    int*   Li = (int*)(smem + 24576);
#pragma unroll
    for (int k = 0; k < CKS; ++k) {
        Ls[tid * CKS + k] = ts[k];
        Li[tid * CKS + k] = ti[k];
    }
    __syncthreads();
    if (tid < BM) {
        const int b0 = (tid * 4 + 0) * CKS, b1 = (tid * 4 + 1) * CKS;
        const int b2 = (tid * 4 + 2) * CKS, b3 = (tid * 4 + 3) * CKS;
        int h0 = 0, h1 = 0, h2 = 0, h3 = 0;
        const size_t ob = ((size_t)(tokbase + tid) * SLABS + slab) * CKS;
#pragma unroll 1
        for (int k = 0; k < CKS; ++k) {
            float s0 = Ls[b0 + h0]; int i0 = Li[b0 + h0];
            float s1 = Ls[b1 + h1]; int i1 = Li[b1 + h1];
            float s2 = Ls[b2 + h2]; int i2 = Li[b2 + h2];
            float s3 = Ls[b3 + h3]; int i3 = Li[b3 + h3];
            float bs = s0; int bi = i0; int bp = 0;
            if (s1 > bs || (s1 == bs && i1 < bi)) { bs = s1; bi = i1; bp = 1; }
            if (s2 > bs || (s2 == bs && i2 < bi)) { bs = s2; bi = i2; bp = 2; }
            if (s3 > bs || (s3 == bs && i3 < bi)) { bs = s3; bi = i3; bp = 3; }
            part_s[ob + k] = bs; part_i[ob + k] = bi;
            if      (bp == 0) ++h0;
            else if (bp == 1) ++h1;
            else if (bp == 2) ++h2;
            else              ++h3;
        }
    }
}

// ---------------------------------------------------------------------------
// K3: merge 192 approx partials -> approx top-32 pool -> exact rescore
// (f32 x, split-f16 W reconstruction) -> exact top-20 -> fine stage.
// ---------------------------------------------------------------------------
__global__ __launch_bounds__(256)
void k3_fine(const float* __restrict__ x, const float* __restrict__ Wenc,
             const float* __restrict__ Kall, const float* __restrict__ Vall,
             const unsigned short* __restrict__ WhT, const unsigned short* __restrict__ WlT,
             const float* __restrict__ part_s, const int* __restrict__ part_i,
             float* __restrict__ out)
{
    const int tok = blockIdx.x;
    const int tid = threadIdx.x;

    __shared__ float xs[DIM];
    __shared__ float qs[RANK];
    __shared__ float ls[NPART];
    __shared__ int   li[NPART];
    __shared__ int   pool[POOL];
    __shared__ float resc[POOL];
    __shared__ int   cand[CK];
    __shared__ float fsc[CK];
    __shared__ float fss[FK];
    __shared__ int   fgi[FK];
    __shared__ float fw[FK];

    ((float4*)xs)[tid] = ((const float4*)(x + (size_t)tok * DIM))[tid];
    if (tid < NPART) {
        ls[tid] = part_s[(size_t)tok * NPART + tid];
        li[tid] = part_i[(size_t)tok * NPART + tid];
    }
    __syncthreads();

    // approx top-32 of 192 via lex rank (idx distinct -> unique ranks)
    if (tid < NPART) {
        float s = ls[tid]; int idx = li[tid];
        int r = 0;
        for (int e = 0; e < NPART; ++e) {
            float s2 = ls[e]; int i2 = li[e];
            r += (s2 > s) || (s2 == s && i2 < idx);
        }
        if (r < POOL) pool[r] = idx;
    }
    __syncthreads();

    // exact rescore of 32 pooled candidates: 8 threads per candidate
    {
        const int c = tid >> 3, oct = tid & 7;
        const int idx = pool[c];
        const ushort4* ph = (const ushort4*)(WhT + (size_t)idx * DIM + oct * 128);
        const ushort4* pl = (const ushort4*)(WlT + (size_t)idx * DIM + oct * 128);
        const float* xp = xs + oct * 128;
        float a = 0.0f;
#pragma unroll 4
        for (int j = 0; j < 32; ++j) {
            ushort4 hv = ph[j], lv = pl[j];
            a = fmaf(xp[j*4+0], (float)__builtin_bit_cast(f16, hv.x) + (float)__builtin_bit_cast(f16, lv.x), a);
            a = fmaf(xp[j*4+1], (float)__builtin_bit_cast(f16, hv.y) + (float)__builtin_bit_cast(f16, lv.y), a);
            a = fmaf(xp[j*4+2], (float)__builtin_bit_cast(f16, hv.z) + (float)__builtin_bit_cast(f16, lv.z), a);
            a = fmaf(xp[j*4+3], (float)__builtin_bit_cast(f16, hv.w) + (float)__builtin_bit_cast(f16, lv.w), a);
        }
        a += __shfl_down(a, 4, 8);
        a += __shfl_down(a, 2, 8);
        a += __shfl_down(a, 1, 8);
        if (oct == 0) resc[c] = a * (1.0f / 1024.0f);   // undo x1024 W scale (exact)
    }
    __syncthreads();

    // exact top-20 of 32 rescored (lex: score desc, idx asc)
    if (tid < POOL) {
        float s = resc[tid]; int idx = pool[tid];
        int r = 0;
        for (int e = 0; e < POOL; ++e)
            r += (resc[e] > s) || (resc[e] == s && pool[e] < idx);
        if (r < CK) cand[r] = idx;
    }
    __syncthreads();

    // query = x . W_enc
    if (tid < RANK) {
        float q = 0.0f;
#pragma unroll 8
        for (int d = 0; d < DIM; ++d)
            q = fmaf(xs[d], Wenc[(size_t)d * RANK + tid], q);
        qs[tid] = q;
    }
    __syncthreads();

    if (tid < CK) {
        const float* Kr = Kall + (size_t)cand[tid] * RANK;
        float s = 0.0f;
#pragma unroll 8
        for (int r = 0; r < RANK; ++r) s = fmaf(qs[r], Kr[r], s);
        fsc[tid] = s * 0.08838834764831845f;   // 1/sqrt(128)
    }
    __syncthreads();

    if (tid < CK) {
        float s = fsc[tid]; int r = 0;
        for (int e = 0; e < CK; ++e)
            r += (fsc[e] > s) || (fsc[e] == s && e < tid);
        if (r < FK) { fss[r] = s; fgi[r] = cand[tid]; }
    }
    __syncthreads();

    if (tid == 0) {
        float m = fss[0];
#pragma unroll
        for (int k = 1; k < FK; ++k) m = fmaxf(m, fss[k]);
        float w[FK]; float sum = 0.0f;
#pragma unroll
        for (int k = 0; k < FK; ++k) { w[k] = expf(fss[k] - m); sum += w[k]; }
        float inv = 1.0f / sum;
#pragma unroll
        for (int k = 0; k < FK; ++k) fw[k] = w[k] * inv;
    }
    __syncthreads();

#pragma unroll
    for (int jj = 0; jj < DIM / 256; ++jj) {
        const int d = tid + jj * 256;
        float o = 0.0f;
#pragma unroll
        for (int f = 0; f < FK; ++f)
            o = fmaf(fw[f], Vall[(size_t)fgi[f] * DIM + d], o);
        out[(size_t)tok * DIM + d] = o;
    }
}

// ---------------------------------------------------------------------------
// Fallback path (round-1, f32 VALU): proven correct if ws is too small.
// ---------------------------------------------------------------------------
__global__ __launch_bounds__(256, 2)
void k1_router_f32(const float* __restrict__ x, const float* __restrict__ Wr,
                   float* __restrict__ part_s, int* __restrict__ part_i)
{
    __shared__ float smem[64][257];
    const int tid     = threadIdx.x;
    const int tokbase = blockIdx.x * 64;
    const int colbase = blockIdx.y * 8192;
    const int mytok   = tid & 63;
    const int mypart  = tid >> 6;

    float ts[CK]; int ti[CK];
#pragma unroll
    for (int k = 0; k < CK; ++k) { ts[k] = -INFINITY; ti[k] = 0x7fffffff; }

#pragma unroll 1
    for (int cg = 0; cg < 32; ++cg) {
        const int n = colbase + cg * 256 + tid;
        float acc[64];
#pragma unroll
        for (int t = 0; t < 64; ++t) acc[t] = 0.0f;
#pragma unroll 1
        for (int dc = 0; dc < DIM; dc += 8) {
            float w[8];
#pragma unroll
            for (int i = 0; i < 8; ++i)
                w[i] = Wr[(size_t)(dc + i) * NCOL + n];
#pragma unroll
            for (int t = 0; t < 64; ++t) {
                const float* xr = x + (size_t)(tokbase + t) * DIM + dc;
#pragma unroll
                for (int i = 0; i < 8; ++i)
                    acc[t] = fmaf(xr[i], w[i], acc[t]);
            }
        }
        __syncthreads();
#pragma unroll
        for (int t = 0; t < 64; ++t) smem[t][tid] = acc[t];
        __syncthreads();
        const int jbase = mypart * 64;
#pragma unroll 1
        for (int j = 0; j < 64; ++j) {
            float v = smem[mytok][jbase + j];
            if (v > ts[CK - 1]) {
                float cv = v; int ci = colbase + cg * 256 + jbase + j;
#pragma unroll
                for (int k = 0; k < CK; ++k) {
                    bool g = cv > ts[k];
                    float os = ts[k]; int oi = ti[k];
                    ts[k] = g ? cv : os; ti[k] = g ? ci : oi;
                    cv = g ? os : cv;   ci = g ? oi : ci;
                }
            }
        }
    }
    __syncthreads();
    float* Ls = &smem[0][0];
    int*   Li = (int*)(Ls + 256 * CK);
#pragma unroll
    for (int k = 0; k < CK; ++k) { Ls[tid * CK + k] = ts[k]; Li[tid * CK + k] = ti[k]; }
    __syncthreads();
    if (tid < 64) {
        const int tok = tid;
        int h0 = 0, h1 = 0, h2 = 0, h3 = 0;
        const size_t ob = ((size_t)(tokbase + tok) * 8 + blockIdx.y) * CK;
#pragma unroll 1
        for (int k = 0; k < CK; ++k) {
            float s0 = Ls[(      tok) * CK + h0]; int i0 = Li[(      tok) * CK + h0];
            float s1 = Ls[( 64 + tok) * CK + h1]; int i1 = Li[( 64 + tok) * CK + h1];
            float s2 = Ls[(128 + tok) * CK + h2]; int i2 = Li[(128 + tok) * CK + h2];
            float s3 = Ls[(192 + tok) * CK + h3]; int i3 = Li[(192 + tok) * CK + h3];
            float bs = s0; int bi = i0; int bp = 0;
            if (s1 > bs || (s1 == bs && i1 < bi)) { bs = s1; bi = i1; bp = 1; }
            if (s2 > bs || (s2 == bs && i2 < bi)) { bs = s2; bi = i2; bp = 2; }
            if (s3 > bs || (s3 == bs && i3 < bi)) { bs = s3; bi = i3; bp = 3; }
            part_s[ob + k] = bs; part_i[ob + k] = bi;
            if      (bp == 0) ++h0;
            else if (bp == 1) ++h1;
            else if (bp == 2) ++h2;
            else              ++h3;
        }
    }
}

template<int CT, int BLK>
__global__ __launch_bounds__(BLK)
void k3_fine_direct(const float* __restrict__ x, const float* __restrict__ Wenc,
                    const float* __restrict__ Kall, const float* __restrict__ Vall,
                    const float* __restrict__ part_s, const int* __restrict__ part_i,
                    float* __restrict__ out)
{
    const int tok = blockIdx.x;
    const int tid = threadIdx.x;

    __shared__ float xs[DIM];
    __shared__ float qs[RANK];
    __shared__ float ls[CT * CK];
    __shared__ int   li[CT * CK];
    __shared__ int   cand[CK];
    __shared__ float fsc[CK];
    __shared__ float fss[FK];
    __shared__ int   fgi[FK];
    __shared__ float fw[FK];

    if (tid < DIM / 4)
        ((float4*)xs)[tid] = ((const float4*)(x + (size_t)tok * DIM))[tid];
    for (int i = tid; i < CT * CK; i += BLK) {
        ls[i] = part_s[(size_t)tok * (CT * CK) + i];
        li[i] = part_i[(size_t)tok * (CT * CK) + i];
    }
    __syncthreads();

    if (tid < CT * CK) {
        float s = ls[tid]; int idx = li[tid];
        int r = 0;
        for (int e = 0; e < CT * CK; ++e) {
            float s2 = ls[e]; int i2 = li[e];
            r += (s2 > s) || (s2 == s && i2 < idx);
        }
        if (r < CK) cand[r] = idx;
    }
    __syncthreads();

    if (tid < RANK) {
        float q = 0.0f;
#pragma unroll 8
        for (int d = 0; d < DIM; ++d)
            q = fmaf(xs[d], Wenc[(size_t)d * RANK + tid], q);
        qs[tid] = q;
    }
    __syncthreads();

    if (tid < CK) {
        const float* Kr = Kall + (size_t)cand[tid] * RANK;
        float s = 0.0f;
#pragma unroll 8
        for (int r = 0; r < RANK; ++r) s = fmaf(qs[r], Kr[r], s);
        fsc[tid] = s * 0.08838834764831845f;
    }
    __syncthreads();

    if (tid < CK) {
        float s = fsc[tid]; int r = 0;
        for (int e = 0; e < CK; ++e)
            r += (fsc[e] > s) || (fsc[e] == s && e < tid);
        if (r < FK) { fss[r] = s; fgi[r] = cand[tid]; }
    }
    __syncthreads();

    if (tid == 0) {
        float m = fss[0];
#pragma unroll
        for (int k = 1; k < FK; ++k) m = fmaxf(m, fss[k]);
        float w[FK]; float sum = 0.0f;
#pragma unroll
        for (int k = 0; k < FK; ++k) { w[k] = expf(fss[k] - m); sum += w[k]; }
        float inv = 1.0f / sum;
#pragma unroll
        for (int k = 0; k < FK; ++k) fw[k] = w[k] * inv;
    }
    __syncthreads();

    for (int d = tid; d < DIM; d += BLK) {
        float o = 0.0f;
#pragma unroll
        for (int f = 0; f < FK; ++f)
            o = fmaf(fw[f], Vall[(size_t)fgi[f] * DIM + d], o);
        out[(size_t)tok * DIM + d] = o;
    }
}

extern "C" void kernel_launch(void* const* d_in, const int* in_sizes, int n_in,
                              void* d_out, int out_size, void* d_ws, size_t ws_size,
                              hipStream_t stream)
{
    (void)in_sizes; (void)n_in; (void)out_size;
    const float* x    = (const float*)d_in[0];
    const float* Wr   = (const float*)d_in[1];
    const float* Wenc = (const float*)d_in[2];
    const float* Kall = (const float*)d_in[3];
    const float* Vall = (const float*)d_in[4];
    float* out = (float*)d_out;

    const size_t off_ps = 0;
    const size_t off_pi = off_ps + (size_t)NTOK * NPART * 4;
    const size_t off_xh = off_pi + (size_t)NTOK * NPART * 4;
    const size_t off_wh = off_xh + (size_t)NTOK * DIM * 2;
    const size_t off_wl = off_wh + (size_t)NCOL * DIM * 2;
    const size_t REQ    = off_wl + (size_t)NCOL * DIM * 2;   // ~270 MiB

    if (ws_size >= REQ) {
        float* part_s = (float*)((char*)d_ws + off_ps);
        int*   part_i = (int*)((char*)d_ws + off_pi);
        unsigned short* xh  = (unsigned short*)((char*)d_ws + off_xh);
        unsigned short* WhT = (unsigned short*)((char*)d_ws + off_wh);
        unsigned short* WlT = (unsigned short*)((char*)d_ws + off_wl);

        k0_convx<<<NTOK * DIM / 1024, 256, 0, stream>>>(x, xh);
        k0_convw<<<dim3(DIM / 64, NCOL / 64), 256, 0, stream>>>(Wr, WhT, WlT);
        k1_mfma<<<dim3(SLABS, NTOK / BM), 512, 0, stream>>>(xh, WhT, part_s, part_i);
        k3_fine<<<NTOK, 256, 0, stream>>>(x, Wenc, Kall, Vall, WhT, WlT, part_s, part_i, out);
    } else {
        float* part_s = (float*)d_ws;
        int*   part_i = (int*)d_ws + (size_t)NTOK * 8 * CK;
        k1_router_f32<<<dim3(NTOK / 64, 8), 256, 0, stream>>>(x, Wr, part_s, part_i);
        k3_fine_direct<8, 256><<<NTOK, 256, 0, stream>>>(x, Wenc, Kall, Vall, part_s, part_i, out);
    }
}